// Round 1
// baseline (257.079 us; speedup 1.0000x reference)
//
#include <hip/hip_runtime.h>
#include <math.h>

#define F_DIM 64
#define G_DIM 64
#define PTS 256   // points per block (== threads per block)
#define GPB 4     // gaussians per block

// ---------------------------------------------------------------------------
// Setup: per-gaussian Cholesky L of covariance, Linv (lower-tri inverse),
// m = Linv * center, k = logdet + F*log(2*pi).  One block (64 threads) per g.
// ---------------------------------------------------------------------------
__global__ __launch_bounds__(64)
void gm_setup(const float* __restrict__ centers,
              const float* __restrict__ cov,
              float* __restrict__ Ainv,    // G*F*F  (Linv, row-major, upper = 0)
              float* __restrict__ mvec,    // G*F
              float* __restrict__ kconst)  // G
{
    __shared__ float a[F_DIM][F_DIM + 1];
    __shared__ float y[F_DIM][F_DIM + 1];
    __shared__ float ld[F_DIM];
    const int g = blockIdx.x;
    const int t = threadIdx.x;   // 0..63
    const float* covg = cov + (size_t)g * F_DIM * F_DIM;

    for (int j = 0; j < F_DIM; ++j) a[t][j] = covg[t * F_DIM + j];
    __syncthreads();

    // Right-looking Cholesky (lower triangle of a becomes L)
    for (int j = 0; j < F_DIM; ++j) {
        if (t == j) a[j][j] = sqrtf(a[j][j]);
        __syncthreads();
        if (t > j) a[t][j] /= a[j][j];
        __syncthreads();
        if (t > j) {
            const float ltj = a[t][j];
            for (int k = j + 1; k <= t; ++k) a[t][k] -= ltj * a[k][j];
        }
        __syncthreads();
    }

    ld[t] = logf(a[t][t]);

    // Invert L by forward substitution: thread t owns column t of Linv.
    {
        const int c = t;
        for (int i = 0; i < c; ++i) y[i][c] = 0.0f;
        y[c][c] = 1.0f / a[c][c];
        for (int i = c + 1; i < F_DIM; ++i) {
            float s = 0.0f;
            for (int k = c; k < i; ++k) s += a[i][k] * y[k][c];
            y[i][c] = -s / a[i][i];
        }
    }
    __syncthreads();

    // Write Linv row t
    for (int j = 0; j < F_DIM; ++j)
        Ainv[(size_t)g * F_DIM * F_DIM + t * F_DIM + j] = y[t][j];

    // m_t = sum_j Linv[t][j] * center[j]   (Linv lower-tri: j <= t)
    const float* cg = centers + g * F_DIM;
    float s = 0.0f;
    for (int j = 0; j <= t; ++j) s += y[t][j] * cg[j];
    mvec[g * F_DIM + t] = s;

    if (t == 0) {
        float sum = 0.0f;
        for (int j = 0; j < F_DIM; ++j) sum += ld[j];
        // log(2*pi) = 1.8378770664093453
        kconst[g] = 2.0f * sum + (float)F_DIM * 1.8378770664093453f;
    }
}

// ---------------------------------------------------------------------------
// Main: out[p][g] = exp(-0.5*(||A_g x_p - m_g||^2 + k_g))
// Thread-per-point, x row in registers, A_g staged in LDS (wave-uniform
// broadcast reads -> conflict-free). GPB gaussians per block.
// ---------------------------------------------------------------------------
__global__ __launch_bounds__(PTS)
void gm_main(const float* __restrict__ x,
             const float* __restrict__ Ainv,
             const float* __restrict__ mvec,
             const float* __restrict__ kconst,
             float* __restrict__ out)
{
    __shared__ float As[F_DIM * F_DIM];   // 16 KiB
    __shared__ float ms[F_DIM];
    const int t = threadIdx.x;
    const size_t p = (size_t)blockIdx.x * PTS + t;
    const int g0 = blockIdx.y * GPB;

    // Load this thread's x row into registers (16 x float4 = 64 floats)
    float xr[F_DIM];
    const float4* xp = (const float4*)(x + p * F_DIM);
#pragma unroll
    for (int j = 0; j < F_DIM / 4; ++j) {
        const float4 v = xp[j];
        xr[4 * j + 0] = v.x; xr[4 * j + 1] = v.y;
        xr[4 * j + 2] = v.z; xr[4 * j + 3] = v.w;
    }

    for (int gi = 0; gi < GPB; ++gi) {
        const int g = g0 + gi;
        __syncthreads();   // protect As/ms reuse across iterations
        // Stage A_g (4096 floats) cooperatively: 256 threads x 4 float4
        const float4* Ag = (const float4*)(Ainv + (size_t)g * F_DIM * F_DIM);
        float4* As4 = (float4*)As;
#pragma unroll
        for (int r = 0; r < 4; ++r) As4[r * PTS + t] = Ag[r * PTS + t];
        if (t < F_DIM) ms[t] = mvec[g * F_DIM + t];
        __syncthreads();
        const float kg = kconst[g];

        float maha = 0.0f;
#pragma unroll 8
        for (int i = 0; i < F_DIM; ++i) {
            const float4* row = (const float4*)(As + i * F_DIM);
            float a0 = 0.0f, a1 = 0.0f, a2 = 0.0f, a3 = 0.0f;
#pragma unroll
            for (int j = 0; j < F_DIM / 4; ++j) {
                const float4 v = row[j];   // wave-uniform -> LDS broadcast
                a0 = fmaf(v.x, xr[4 * j + 0], a0);
                a1 = fmaf(v.y, xr[4 * j + 1], a1);
                a2 = fmaf(v.z, xr[4 * j + 2], a2);
                a3 = fmaf(v.w, xr[4 * j + 3], a3);
            }
            const float z = ((a0 + a2) + (a1 + a3)) - ms[i];
            maha = fmaf(z, z, maha);
        }
        out[p * G_DIM + g] = expf(-0.5f * (maha + kg));
    }
}

// ---------------------------------------------------------------------------
extern "C" void kernel_launch(void* const* d_in, const int* in_sizes, int n_in,
                              void* d_out, int out_size, void* d_ws, size_t ws_size,
                              hipStream_t stream) {
    const float* x       = (const float*)d_in[0];
    const float* centers = (const float*)d_in[1];
    const float* cov     = (const float*)d_in[2];
    float* out = (float*)d_out;

    char* ws = (char*)d_ws;
    const size_t ainv_bytes = (size_t)G_DIM * F_DIM * F_DIM * sizeof(float); // 1 MiB
    const size_t m_bytes    = (size_t)G_DIM * F_DIM * sizeof(float);
    float* Ainv   = (float*)(ws);
    float* mvec   = (float*)(ws + ainv_bytes);
    float* kconst = (float*)(ws + ainv_bytes + m_bytes);

    const int npts = in_sizes[0] / F_DIM;   // 16384

    gm_setup<<<G_DIM, F_DIM, 0, stream>>>(centers, cov, Ainv, mvec, kconst);

    dim3 grid(npts / PTS, G_DIM / GPB);
    gm_main<<<grid, PTS, 0, stream>>>(x, Ainv, mvec, kconst, out);
}

// Round 2
// 134.083 us; speedup vs baseline: 1.9173x; 1.9173x over previous
//
#include <hip/hip_runtime.h>
#include <math.h>

#define F_DIM 64
#define G_DIM 64
#define PTS 256   // points per block (== threads per block)
#define GPB 4     // gaussians per block

// ---------------------------------------------------------------------------
// Setup: per-gaussian Cholesky L of covariance, Linv (lower-tri inverse),
// m = Linv * center, k = logdet + F*log(2*pi).  One block (64 threads) per g.
// Also: detect exactly-diagonal covariance (offflag stays 0) and emit the
// diagonal of Linv packed (diagv) for the diagonal fast path.
// ---------------------------------------------------------------------------
__global__ __launch_bounds__(64)
void gm_setup(const float* __restrict__ centers,
              const float* __restrict__ cov,
              float* __restrict__ Ainv,    // G*F*F  (Linv, row-major, upper = 0)
              float* __restrict__ diagv,   // G*F    (diag of Linv)
              float* __restrict__ mvec,    // G*F
              float* __restrict__ kconst,  // G
              int*   __restrict__ offflag) // 1 int, pre-zeroed; 1 => has offdiag
{
    __shared__ float a[F_DIM][F_DIM + 1];
    __shared__ float y[F_DIM][F_DIM + 1];
    __shared__ float ld[F_DIM];
    const int g = blockIdx.x;
    const int t = threadIdx.x;   // 0..63
    const float* covg = cov + (size_t)g * F_DIM * F_DIM;

    for (int j = 0; j < F_DIM; ++j) a[t][j] = covg[t * F_DIM + j];
    __syncthreads();

    // Diagonality check on the original matrix (before Cholesky overwrites it)
    {
        int bad = 0;
        for (int j = 0; j < F_DIM; ++j)
            if (j != t && a[t][j] != 0.0f) bad = 1;
        if (bad) atomicOr(offflag, 1);
    }

    // Right-looking Cholesky (lower triangle of a becomes L)
    for (int j = 0; j < F_DIM; ++j) {
        if (t == j) a[j][j] = sqrtf(a[j][j]);
        __syncthreads();
        if (t > j) a[t][j] /= a[j][j];
        __syncthreads();
        if (t > j) {
            const float ltj = a[t][j];
            for (int k = j + 1; k <= t; ++k) a[t][k] -= ltj * a[k][j];
        }
        __syncthreads();
    }

    ld[t] = logf(a[t][t]);

    // Invert L by forward substitution: thread t owns column t of Linv.
    {
        const int c = t;
        for (int i = 0; i < c; ++i) y[i][c] = 0.0f;
        y[c][c] = 1.0f / a[c][c];
        for (int i = c + 1; i < F_DIM; ++i) {
            float s = 0.0f;
            for (int k = c; k < i; ++k) s += a[i][k] * y[k][c];
            y[i][c] = -s / a[i][i];
        }
    }
    __syncthreads();

    // Write Linv row t, packed diagonal
    for (int j = 0; j < F_DIM; ++j)
        Ainv[(size_t)g * F_DIM * F_DIM + t * F_DIM + j] = y[t][j];
    diagv[g * F_DIM + t] = y[t][t];

    // m_t = sum_j Linv[t][j] * center[j]   (Linv lower-tri: j <= t)
    const float* cg = centers + g * F_DIM;
    float s = 0.0f;
    for (int j = 0; j <= t; ++j) s += y[t][j] * cg[j];
    mvec[g * F_DIM + t] = s;

    if (t == 0) {
        float sum = 0.0f;
        for (int j = 0; j < F_DIM; ++j) sum += ld[j];
        // log(2*pi) = 1.8378770664093453
        kconst[g] = 2.0f * sum + (float)F_DIM * 1.8378770664093453f;
    }
}

// ---------------------------------------------------------------------------
// Main: out[p][g] = exp(-0.5*(||A_g x_p - m_g||^2 + k_g))
// Grid-uniform branch on offflag:
//   diag path:    maha = sum_j (x_j*d_j - m_j)^2      (F work per pair)
//   general path: thread-per-point, A_g staged in LDS  (F^2 work per pair)
// ---------------------------------------------------------------------------
__global__ __launch_bounds__(PTS)
void gm_main(const float* __restrict__ x,
             const float* __restrict__ Ainv,
             const float* __restrict__ diagv,
             const float* __restrict__ mvec,
             const float* __restrict__ kconst,
             const int* __restrict__ offflag,
             float* __restrict__ out)
{
    __shared__ float As[F_DIM * F_DIM];   // 16 KiB (general path only)
    __shared__ float ms[F_DIM];
    const int t = threadIdx.x;
    const size_t p = (size_t)blockIdx.x * PTS + t;
    const int g0 = blockIdx.y * GPB;

    // Load this thread's x row into registers (16 x float4 = 64 floats)
    float xr[F_DIM];
    const float4* xp = (const float4*)(x + p * F_DIM);
#pragma unroll
    for (int j = 0; j < F_DIM / 4; ++j) {
        const float4 v = xp[j];
        xr[4 * j + 0] = v.x; xr[4 * j + 1] = v.y;
        xr[4 * j + 2] = v.z; xr[4 * j + 3] = v.w;
    }

    if (offflag[0] == 0) {
        // ---------------- diagonal fast path ----------------
        float o[GPB];
#pragma unroll
        for (int gi = 0; gi < GPB; ++gi) {
            const int g = g0 + gi;
            const float4* dv = (const float4*)(diagv + g * F_DIM);
            const float4* mv = (const float4*)(mvec + g * F_DIM);
            float m0 = 0.0f, m1 = 0.0f, m2 = 0.0f, m3 = 0.0f;
#pragma unroll
            for (int j = 0; j < F_DIM / 4; ++j) {
                const float4 d = dv[j];   // wave-uniform -> s_load / L1 hit
                const float4 m = mv[j];
                const float z0 = fmaf(xr[4 * j + 0], d.x, -m.x);
                const float z1 = fmaf(xr[4 * j + 1], d.y, -m.y);
                const float z2 = fmaf(xr[4 * j + 2], d.z, -m.z);
                const float z3 = fmaf(xr[4 * j + 3], d.w, -m.w);
                m0 = fmaf(z0, z0, m0);
                m1 = fmaf(z1, z1, m1);
                m2 = fmaf(z2, z2, m2);
                m3 = fmaf(z3, z3, m3);
            }
            const float maha = (m0 + m1) + (m2 + m3);
            o[gi] = expf(-0.5f * (maha + kconst[g]));
        }
        float4 r;
        r.x = o[0]; r.y = o[1]; r.z = o[2]; r.w = o[3];
        *(float4*)(out + p * G_DIM + g0) = r;
    } else {
        // ---------------- general path (unchanged) ----------------
        for (int gi = 0; gi < GPB; ++gi) {
            const int g = g0 + gi;
            __syncthreads();   // protect As/ms reuse across iterations
            const float4* Ag = (const float4*)(Ainv + (size_t)g * F_DIM * F_DIM);
            float4* As4 = (float4*)As;
#pragma unroll
            for (int r = 0; r < 4; ++r) As4[r * PTS + t] = Ag[r * PTS + t];
            if (t < F_DIM) ms[t] = mvec[g * F_DIM + t];
            __syncthreads();
            const float kg = kconst[g];

            float maha = 0.0f;
#pragma unroll 8
            for (int i = 0; i < F_DIM; ++i) {
                const float4* row = (const float4*)(As + i * F_DIM);
                float a0 = 0.0f, a1 = 0.0f, a2 = 0.0f, a3 = 0.0f;
#pragma unroll
                for (int j = 0; j < F_DIM / 4; ++j) {
                    const float4 v = row[j];   // wave-uniform -> LDS broadcast
                    a0 = fmaf(v.x, xr[4 * j + 0], a0);
                    a1 = fmaf(v.y, xr[4 * j + 1], a1);
                    a2 = fmaf(v.z, xr[4 * j + 2], a2);
                    a3 = fmaf(v.w, xr[4 * j + 3], a3);
                }
                const float z = ((a0 + a2) + (a1 + a3)) - ms[i];
                maha = fmaf(z, z, maha);
            }
            out[p * G_DIM + g] = expf(-0.5f * (maha + kg));
        }
    }
}

// ---------------------------------------------------------------------------
extern "C" void kernel_launch(void* const* d_in, const int* in_sizes, int n_in,
                              void* d_out, int out_size, void* d_ws, size_t ws_size,
                              hipStream_t stream) {
    const float* x       = (const float*)d_in[0];
    const float* centers = (const float*)d_in[1];
    const float* cov     = (const float*)d_in[2];
    float* out = (float*)d_out;

    char* ws = (char*)d_ws;
    const size_t ainv_bytes = (size_t)G_DIM * F_DIM * F_DIM * sizeof(float); // 1 MiB
    const size_t gf_bytes   = (size_t)G_DIM * F_DIM * sizeof(float);         // 16 KiB
    float* Ainv   = (float*)(ws);
    float* mvec   = (float*)(ws + ainv_bytes);
    float* kconst = (float*)(ws + ainv_bytes + gf_bytes);
    float* diagv  = (float*)(ws + ainv_bytes + gf_bytes + 1024);
    int*   offflag= (int*)  (ws + ainv_bytes + gf_bytes + 1024 + gf_bytes);

    const int npts = in_sizes[0] / F_DIM;   // 16384

    hipMemsetAsync(offflag, 0, sizeof(int), stream);
    gm_setup<<<G_DIM, F_DIM, 0, stream>>>(centers, cov, Ainv, diagv, mvec,
                                          kconst, offflag);

    dim3 grid(npts / PTS, G_DIM / GPB);
    gm_main<<<grid, PTS, 0, stream>>>(x, Ainv, diagv, mvec, kconst, offflag, out);
}

// Round 3
// 27.885 us; speedup vs baseline: 9.2193x; 4.8084x over previous
//
#include <hip/hip_runtime.h>
#include <math.h>

#define F_DIM 64
#define G_DIM 64
#define PTS 256   // points per block (== threads per block)
#define GPB 8     // gaussians per block (diag path)
#define LOG2PI 1.8378770664093453f

// ---------------------------------------------------------------------------
// Setup: one block (64 threads = 1 wave) per gaussian.
// Fast path (covariance exactly diagonal): closed-form Linv/m/k, coalesced.
// Slow path: Cholesky + triangular inverse (latency-bound, fallback only).
// ---------------------------------------------------------------------------
__global__ __launch_bounds__(64)
void gm_setup(const float* __restrict__ centers,
              const float* __restrict__ cov,
              float* __restrict__ Ainv,    // G*F*F  (Linv, row-major, upper = 0)
              float* __restrict__ diagv,   // G*F    (diag of Linv)
              float* __restrict__ mvec,    // G*F
              float* __restrict__ kconst,  // G
              int*   __restrict__ offflag) // 1 int, pre-zeroed; 1 => any offdiag
{
    __shared__ float a[F_DIM][F_DIM + 1];
    __shared__ float y[F_DIM][F_DIM + 1];
    __shared__ float ld[F_DIM];
    __shared__ float dsh[F_DIM];
    __shared__ float rsh[F_DIM];
    const int g = blockIdx.x;
    const int t = threadIdx.x;   // 0..63
    const float* covg = cov + (size_t)g * F_DIM * F_DIM;

    // Coalesced sweep: check off-diagonals, capture diagonal values.
    int bad = 0;
    const float4* cov4 = (const float4*)covg;
#pragma unroll
    for (int i = 0; i < 16; ++i) {
        const float4 v = cov4[i * 64 + t];
        const int base = (i * 64 + t) * 4;
        const float vv[4] = {v.x, v.y, v.z, v.w};
#pragma unroll
        for (int c = 0; c < 4; ++c) {
            const int flat = base + c;
            const int r = flat >> 6, col = flat & 63;
            if (r == col) dsh[r] = vv[c];
            else if (vv[c] != 0.0f) bad = 1;
        }
    }
    const unsigned long long anybad = __ballot(bad);
    __syncthreads();

    if (anybad == 0ull) {
        // -------- diagonal fast path --------
        const float d  = dsh[t];
        const float rs = 1.0f / sqrtf(d);
        rsh[t] = rs;
        diagv[g * F_DIM + t] = rs;
        mvec[g * F_DIM + t]  = centers[g * F_DIM + t] * rs;

        // logdet = sum log d ; butterfly-reduce across the wave
        float lg = logf(d);
#pragma unroll
        for (int off = 1; off < 64; off <<= 1) lg += __shfl_xor(lg, off);
        if (t == 0) kconst[g] = lg + (float)F_DIM * LOG2PI;
        __syncthreads();

        // Ainv = diag(rs): coalesced float4 writes
        float4* A4 = (float4*)(Ainv + (size_t)g * F_DIM * F_DIM);
#pragma unroll
        for (int i = 0; i < 16; ++i) {
            const int base = (i * 64 + t) * 4;
            float4 v;
            float vv[4];
#pragma unroll
            for (int c = 0; c < 4; ++c) {
                const int flat = base + c;
                const int r = flat >> 6, col = flat & 63;
                vv[c] = (r == col) ? rsh[r] : 0.0f;
            }
            v.x = vv[0]; v.y = vv[1]; v.z = vv[2]; v.w = vv[3];
            A4[i * 64 + t] = v;
        }
        return;
    }

    // -------- general fallback: Cholesky + inverse --------
    if (t == 0) atomicOr(offflag, 1);

    for (int j = 0; j < F_DIM; ++j) a[t][j] = covg[t * F_DIM + j];
    __syncthreads();

    for (int j = 0; j < F_DIM; ++j) {
        if (t == j) a[j][j] = sqrtf(a[j][j]);
        __syncthreads();
        if (t > j) a[t][j] /= a[j][j];
        __syncthreads();
        if (t > j) {
            const float ltj = a[t][j];
            for (int k = j + 1; k <= t; ++k) a[t][k] -= ltj * a[k][j];
        }
        __syncthreads();
    }

    ld[t] = logf(a[t][t]);

    {   // thread t owns column t of Linv
        const int c = t;
        for (int i = 0; i < c; ++i) y[i][c] = 0.0f;
        y[c][c] = 1.0f / a[c][c];
        for (int i = c + 1; i < F_DIM; ++i) {
            float s = 0.0f;
            for (int k = c; k < i; ++k) s += a[i][k] * y[k][c];
            y[i][c] = -s / a[i][i];
        }
    }
    __syncthreads();

    for (int j = 0; j < F_DIM; ++j)
        Ainv[(size_t)g * F_DIM * F_DIM + t * F_DIM + j] = y[t][j];
    diagv[g * F_DIM + t] = y[t][t];

    const float* cg = centers + g * F_DIM;
    float s = 0.0f;
    for (int j = 0; j <= t; ++j) s += y[t][j] * cg[j];
    mvec[g * F_DIM + t] = s;

    if (t == 0) {
        float sum = 0.0f;
        for (int j = 0; j < F_DIM; ++j) sum += ld[j];
        kconst[g] = 2.0f * sum + (float)F_DIM * LOG2PI;
    }
}

// ---------------------------------------------------------------------------
// Main: out[p][g] = exp(-0.5*(||A_g x_p - m_g||^2 + k_g))
// Grid-uniform branch on offflag:
//   diag path:    maha = sum_j (x_j*d_j - m_j)^2 ; d/m/k staged in LDS
//   general path: thread-per-point, A_g staged in LDS  (F^2 work per pair)
// ---------------------------------------------------------------------------
__global__ __launch_bounds__(PTS)
void gm_main(const float* __restrict__ x,
             const float* __restrict__ Ainv,
             const float* __restrict__ diagv,
             const float* __restrict__ mvec,
             const float* __restrict__ kconst,
             const int* __restrict__ offflag,
             float* __restrict__ out)
{
    __shared__ float As[F_DIM * F_DIM];   // 16 KiB; diag path aliases into it
    __shared__ float ms[F_DIM];
    const int t = threadIdx.x;
    const size_t p = (size_t)blockIdx.x * PTS + t;
    const int g0 = blockIdx.y * GPB;

    // This thread's x row -> registers (16 x float4)
    float xr[F_DIM];
    const float4* xp = (const float4*)(x + p * F_DIM);
#pragma unroll
    for (int j = 0; j < F_DIM / 4; ++j) {
        const float4 v = xp[j];
        xr[4 * j + 0] = v.x; xr[4 * j + 1] = v.y;
        xr[4 * j + 2] = v.z; xr[4 * j + 3] = v.w;
    }

    if (offflag[0] == 0) {
        // ---------------- diagonal fast path ----------------
        float* Ds = As;                    // GPB*64 floats
        float* Ms = As + GPB * F_DIM;      // GPB*64 floats
        float* Kc = As + 2 * GPB * F_DIM;  // GPB floats
        // Stage coefficients once per block (coalesced float2 loads)
        ((float2*)Ds)[t] = ((const float2*)(diagv + g0 * F_DIM))[t];
        ((float2*)Ms)[t] = ((const float2*)(mvec  + g0 * F_DIM))[t];
        if (t < GPB) Kc[t] = kconst[g0 + t];
        __syncthreads();

        float o[GPB];
#pragma unroll
        for (int gi = 0; gi < GPB; ++gi) {
            const float4* dv = (const float4*)(Ds + gi * F_DIM);
            const float4* mv = (const float4*)(Ms + gi * F_DIM);
            float m0 = 0.0f, m1 = 0.0f, m2 = 0.0f, m3 = 0.0f;
#pragma unroll
            for (int j = 0; j < F_DIM / 4; ++j) {
                const float4 d = dv[j];   // wave-uniform -> LDS broadcast
                const float4 m = mv[j];
                const float z0 = fmaf(xr[4 * j + 0], d.x, -m.x);
                const float z1 = fmaf(xr[4 * j + 1], d.y, -m.y);
                const float z2 = fmaf(xr[4 * j + 2], d.z, -m.z);
                const float z3 = fmaf(xr[4 * j + 3], d.w, -m.w);
                m0 = fmaf(z0, z0, m0);
                m1 = fmaf(z1, z1, m1);
                m2 = fmaf(z2, z2, m2);
                m3 = fmaf(z3, z3, m3);
            }
            const float maha = (m0 + m1) + (m2 + m3);
            o[gi] = __expf(-0.5f * (maha + Kc[gi]));
        }
        float4 r0, r1;
        r0.x = o[0]; r0.y = o[1]; r0.z = o[2]; r0.w = o[3];
        r1.x = o[4]; r1.y = o[5]; r1.z = o[6]; r1.w = o[7];
        float4* op = (float4*)(out + p * G_DIM + g0);
        op[0] = r0;
        op[1] = r1;
    } else {
        // ---------------- general path ----------------
        for (int gi = 0; gi < GPB; ++gi) {
            const int g = g0 + gi;
            __syncthreads();   // protect As/ms reuse across iterations
            const float4* Ag = (const float4*)(Ainv + (size_t)g * F_DIM * F_DIM);
            float4* As4 = (float4*)As;
#pragma unroll
            for (int r = 0; r < 4; ++r) As4[r * PTS + t] = Ag[r * PTS + t];
            if (t < F_DIM) ms[t] = mvec[g * F_DIM + t];
            __syncthreads();
            const float kg = kconst[g];

            float maha = 0.0f;
#pragma unroll 8
            for (int i = 0; i < F_DIM; ++i) {
                const float4* row = (const float4*)(As + i * F_DIM);
                float a0 = 0.0f, a1 = 0.0f, a2 = 0.0f, a3 = 0.0f;
#pragma unroll
                for (int j = 0; j < F_DIM / 4; ++j) {
                    const float4 v = row[j];
                    a0 = fmaf(v.x, xr[4 * j + 0], a0);
                    a1 = fmaf(v.y, xr[4 * j + 1], a1);
                    a2 = fmaf(v.z, xr[4 * j + 2], a2);
                    a3 = fmaf(v.w, xr[4 * j + 3], a3);
                }
                const float z = ((a0 + a2) + (a1 + a3)) - ms[i];
                maha = fmaf(z, z, maha);
            }
            out[p * G_DIM + g] = __expf(-0.5f * (maha + kg));
        }
    }
}

// ---------------------------------------------------------------------------
extern "C" void kernel_launch(void* const* d_in, const int* in_sizes, int n_in,
                              void* d_out, int out_size, void* d_ws, size_t ws_size,
                              hipStream_t stream) {
    const float* x       = (const float*)d_in[0];
    const float* centers = (const float*)d_in[1];
    const float* cov     = (const float*)d_in[2];
    float* out = (float*)d_out;

    char* ws = (char*)d_ws;
    const size_t ainv_bytes = (size_t)G_DIM * F_DIM * F_DIM * sizeof(float); // 1 MiB
    const size_t gf_bytes   = (size_t)G_DIM * F_DIM * sizeof(float);         // 16 KiB
    float* Ainv   = (float*)(ws);
    float* mvec   = (float*)(ws + ainv_bytes);
    float* kconst = (float*)(ws + ainv_bytes + gf_bytes);
    float* diagv  = (float*)(ws + ainv_bytes + gf_bytes + 1024);
    int*   offflag= (int*)  (ws + ainv_bytes + gf_bytes + 1024 + gf_bytes);

    const int npts = in_sizes[0] / F_DIM;   // 16384

    hipMemsetAsync(offflag, 0, sizeof(int), stream);
    gm_setup<<<G_DIM, F_DIM, 0, stream>>>(centers, cov, Ainv, diagv, mvec,
                                          kconst, offflag);

    dim3 grid(npts / PTS, G_DIM / GPB);
    gm_main<<<grid, PTS, 0, stream>>>(x, Ainv, diagv, mvec, kconst, offflag, out);
}

// Round 4
// 22.536 us; speedup vs baseline: 11.4074x; 1.2373x over previous
//
#include <hip/hip_runtime.h>
#include <math.h>

#define F_DIM 64
#define G_DIM 64
#define PTS 256   // points per block (== threads per block)
#define GPB 8     // gaussians per block
#define LOG2PI 1.8378770664093453f

// ---------------------------------------------------------------------------
// Setup: one block (64 threads = 1 wave) per gaussian.
// Diag fast path: closed-form coefficients only (no Ainv fill, no Cholesky).
// Fallback: Cholesky + triangular inverse, writes Ainv.
// gflag[g] written unconditionally (0=diag, 1=general) -> no memset needed.
// ---------------------------------------------------------------------------
__global__ __launch_bounds__(64)
void gm_setup(const float* __restrict__ centers,
              const float* __restrict__ cov,
              float* __restrict__ Ainv,    // G*F*F  (general path only)
              float* __restrict__ diagv,   // G*F    (diag of Linv)
              float* __restrict__ mvec,    // G*F
              float* __restrict__ kconst,  // G
              int*   __restrict__ gflag)   // G  (written every call)
{
    __shared__ float a[F_DIM][F_DIM + 1];
    __shared__ float y[F_DIM][F_DIM + 1];
    __shared__ float ld[F_DIM];
    __shared__ float dsh[F_DIM];
    const int g = blockIdx.x;
    const int t = threadIdx.x;   // 0..63
    const float* covg = cov + (size_t)g * F_DIM * F_DIM;

    // Coalesced sweep: check off-diagonals, capture diagonal values.
    int bad = 0;
    const float4* cov4 = (const float4*)covg;
#pragma unroll
    for (int i = 0; i < 16; ++i) {
        const float4 v = cov4[i * 64 + t];
        const int base = (i * 64 + t) * 4;
        const float vv[4] = {v.x, v.y, v.z, v.w};
#pragma unroll
        for (int c = 0; c < 4; ++c) {
            const int flat = base + c;
            const int r = flat >> 6, col = flat & 63;
            if (r == col) dsh[r] = vv[c];
            else if (vv[c] != 0.0f) bad = 1;
        }
    }
    const unsigned long long anybad = __ballot(bad);
    __syncthreads();

    if (t == 0) gflag[g] = (anybad != 0ull) ? 1 : 0;

    if (anybad == 0ull) {
        // -------- diagonal fast path: coefficients only --------
        const float d  = dsh[t];
        const float rs = 1.0f / sqrtf(d);
        diagv[g * F_DIM + t] = rs;
        mvec[g * F_DIM + t]  = centers[g * F_DIM + t] * rs;

        float lg = logf(d);
#pragma unroll
        for (int off = 1; off < 64; off <<= 1) lg += __shfl_xor(lg, off);
        if (t == 0) kconst[g] = lg + (float)F_DIM * LOG2PI;
        return;
    }

    // -------- general fallback: Cholesky + inverse --------
    for (int j = 0; j < F_DIM; ++j) a[t][j] = covg[t * F_DIM + j];
    __syncthreads();

    for (int j = 0; j < F_DIM; ++j) {
        if (t == j) a[j][j] = sqrtf(a[j][j]);
        __syncthreads();
        if (t > j) a[t][j] /= a[j][j];
        __syncthreads();
        if (t > j) {
            const float ltj = a[t][j];
            for (int k = j + 1; k <= t; ++k) a[t][k] -= ltj * a[k][j];
        }
        __syncthreads();
    }

    ld[t] = logf(a[t][t]);

    {   // thread t owns column t of Linv
        const int c = t;
        for (int i = 0; i < c; ++i) y[i][c] = 0.0f;
        y[c][c] = 1.0f / a[c][c];
        for (int i = c + 1; i < F_DIM; ++i) {
            float s = 0.0f;
            for (int k = c; k < i; ++k) s += a[i][k] * y[k][c];
            y[i][c] = -s / a[i][i];
        }
    }
    __syncthreads();

    for (int j = 0; j < F_DIM; ++j)
        Ainv[(size_t)g * F_DIM * F_DIM + t * F_DIM + j] = y[t][j];
    diagv[g * F_DIM + t] = y[t][t];   // unused when gflag=1; harmless

    const float* cg = centers + g * F_DIM;
    float s = 0.0f;
    for (int j = 0; j <= t; ++j) s += y[t][j] * cg[j];
    mvec[g * F_DIM + t] = s;

    if (t == 0) {
        float sum = 0.0f;
        for (int j = 0; j < F_DIM; ++j) sum += ld[j];
        kconst[g] = 2.0f * sum + (float)F_DIM * LOG2PI;
    }
}

// ---------------------------------------------------------------------------
// Main: out[p][g] = exp(-0.5*(maha + k_g))
// Per-gaussian block-uniform branch on gflag[g]:
//   diag:    maha = sum_j (x_j*d_j - m_j)^2           (coeffs staged in LDS)
//   general: maha = ||A_g x - m_g||^2, A_g staged in LDS (16 KiB tile)
// ---------------------------------------------------------------------------
__global__ __launch_bounds__(PTS)
void gm_main(const float* __restrict__ x,
             const float* __restrict__ Ainv,
             const float* __restrict__ diagv,
             const float* __restrict__ mvec,
             const float* __restrict__ kconst,
             const int* __restrict__ gflag,
             float* __restrict__ out)
{
    __shared__ float As[F_DIM * F_DIM];   // general path only
    __shared__ float Ds[GPB * F_DIM];
    __shared__ float Ms[GPB * F_DIM];
    __shared__ float Kc[GPB];
    const int t = threadIdx.x;
    const size_t p = (size_t)blockIdx.x * PTS + t;
    const int g0 = blockIdx.y * GPB;

    // This thread's x row -> registers (16 x float4)
    float xr[F_DIM];
    const float4* xp = (const float4*)(x + p * F_DIM);
#pragma unroll
    for (int j = 0; j < F_DIM / 4; ++j) {
        const float4 v = xp[j];
        xr[4 * j + 0] = v.x; xr[4 * j + 1] = v.y;
        xr[4 * j + 2] = v.z; xr[4 * j + 3] = v.w;
    }

    // Stage per-gaussian coefficients once per block (coalesced float2)
    ((float2*)Ds)[t] = ((const float2*)(diagv + g0 * F_DIM))[t];
    ((float2*)Ms)[t] = ((const float2*)(mvec  + g0 * F_DIM))[t];
    if (t < GPB) Kc[t] = kconst[g0 + t];

    int anyoff = 0;
#pragma unroll
    for (int gi = 0; gi < GPB; ++gi) anyoff |= gflag[g0 + gi];
    __syncthreads();

    if (anyoff == 0) {
        // ---------------- all-diagonal fast path ----------------
        float o[GPB];
#pragma unroll
        for (int gi = 0; gi < GPB; ++gi) {
            const float4* dv = (const float4*)(Ds + gi * F_DIM);
            const float4* mv = (const float4*)(Ms + gi * F_DIM);
            float m0 = 0.0f, m1 = 0.0f, m2 = 0.0f, m3 = 0.0f;
#pragma unroll
            for (int j = 0; j < F_DIM / 4; ++j) {
                const float4 d = dv[j];   // wave-uniform -> LDS broadcast
                const float4 m = mv[j];
                const float z0 = fmaf(xr[4 * j + 0], d.x, -m.x);
                const float z1 = fmaf(xr[4 * j + 1], d.y, -m.y);
                const float z2 = fmaf(xr[4 * j + 2], d.z, -m.z);
                const float z3 = fmaf(xr[4 * j + 3], d.w, -m.w);
                m0 = fmaf(z0, z0, m0);
                m1 = fmaf(z1, z1, m1);
                m2 = fmaf(z2, z2, m2);
                m3 = fmaf(z3, z3, m3);
            }
            const float maha = (m0 + m1) + (m2 + m3);
            o[gi] = __expf(-0.5f * (maha + Kc[gi]));
        }
        float4 r0, r1;
        r0.x = o[0]; r0.y = o[1]; r0.z = o[2]; r0.w = o[3];
        r1.x = o[4]; r1.y = o[5]; r1.z = o[6]; r1.w = o[7];
        float4* op = (float4*)(out + p * G_DIM + g0);
        op[0] = r0;
        op[1] = r1;
    } else {
        // ---------------- mixed / general path ----------------
        float o[GPB];
        for (int gi = 0; gi < GPB; ++gi) {
            const int g = g0 + gi;
            float maha = 0.0f;
            if (gflag[g] == 0) {           // block-uniform branch
                const float4* dv = (const float4*)(Ds + gi * F_DIM);
                const float4* mv = (const float4*)(Ms + gi * F_DIM);
                float m0 = 0.0f, m1 = 0.0f, m2 = 0.0f, m3 = 0.0f;
#pragma unroll
                for (int j = 0; j < F_DIM / 4; ++j) {
                    const float4 d = dv[j];
                    const float4 m = mv[j];
                    const float z0 = fmaf(xr[4 * j + 0], d.x, -m.x);
                    const float z1 = fmaf(xr[4 * j + 1], d.y, -m.y);
                    const float z2 = fmaf(xr[4 * j + 2], d.z, -m.z);
                    const float z3 = fmaf(xr[4 * j + 3], d.w, -m.w);
                    m0 = fmaf(z0, z0, m0);
                    m1 = fmaf(z1, z1, m1);
                    m2 = fmaf(z2, z2, m2);
                    m3 = fmaf(z3, z3, m3);
                }
                maha = (m0 + m1) + (m2 + m3);
            } else {
                __syncthreads();   // As reuse (uniform: gflag same blockwide)
                const float4* Ag = (const float4*)(Ainv + (size_t)g * F_DIM * F_DIM);
                float4* As4 = (float4*)As;
#pragma unroll
                for (int r = 0; r < 4; ++r) As4[r * PTS + t] = Ag[r * PTS + t];
                __syncthreads();
#pragma unroll 8
                for (int i = 0; i < F_DIM; ++i) {
                    const float4* row = (const float4*)(As + i * F_DIM);
                    float a0 = 0.0f, a1 = 0.0f, a2 = 0.0f, a3 = 0.0f;
#pragma unroll
                    for (int j = 0; j < F_DIM / 4; ++j) {
                        const float4 v = row[j];
                        a0 = fmaf(v.x, xr[4 * j + 0], a0);
                        a1 = fmaf(v.y, xr[4 * j + 1], a1);
                        a2 = fmaf(v.z, xr[4 * j + 2], a2);
                        a3 = fmaf(v.w, xr[4 * j + 3], a3);
                    }
                    const float z = ((a0 + a2) + (a1 + a3)) - Ms[gi * F_DIM + i];
                    maha = fmaf(z, z, maha);
                }
            }
            o[gi] = __expf(-0.5f * (maha + Kc[gi]));
        }
#pragma unroll
        for (int gi = 0; gi < GPB; ++gi) out[p * G_DIM + g0 + gi] = o[gi];
    }
}

// ---------------------------------------------------------------------------
extern "C" void kernel_launch(void* const* d_in, const int* in_sizes, int n_in,
                              void* d_out, int out_size, void* d_ws, size_t ws_size,
                              hipStream_t stream) {
    const float* x       = (const float*)d_in[0];
    const float* centers = (const float*)d_in[1];
    const float* cov     = (const float*)d_in[2];
    float* out = (float*)d_out;

    char* ws = (char*)d_ws;
    const size_t ainv_bytes = (size_t)G_DIM * F_DIM * F_DIM * sizeof(float); // 1 MiB
    const size_t gf_bytes   = (size_t)G_DIM * F_DIM * sizeof(float);         // 16 KiB
    float* Ainv   = (float*)(ws);
    float* mvec   = (float*)(ws + ainv_bytes);
    float* kconst = (float*)(ws + ainv_bytes + gf_bytes);
    float* diagv  = (float*)(ws + ainv_bytes + gf_bytes + 1024);
    int*   gflag  = (int*)  (ws + ainv_bytes + gf_bytes + 1024 + gf_bytes);

    const int npts = in_sizes[0] / F_DIM;   // 16384

    gm_setup<<<G_DIM, F_DIM, 0, stream>>>(centers, cov, Ainv, diagv, mvec,
                                          kconst, gflag);

    dim3 grid(npts / PTS, G_DIM / GPB);
    gm_main<<<grid, PTS, 0, stream>>>(x, Ainv, diagv, mvec, kconst, gflag, out);
}

// Round 5
// 21.079 us; speedup vs baseline: 12.1960x; 1.0691x over previous
//
#include <hip/hip_runtime.h>
#include <math.h>

#define F_DIM 64
#define G_DIM 64
#define PTS 256   // threads per block
#define GPB 8     // gaussians per block (general/mixed path)
#define PPW 8     // points per wave (diag path); block = 4 waves = 32 points
#define LOG2PI 1.8378770664093453f

// ---------------------------------------------------------------------------
// Setup: one block (64 threads = 1 wave) per gaussian.
// Diag fast path: closed-form coefficients; writes BOTH row-major (diagv/mvec,
// for the mixed fallback) and transposed-interleaved cmT[j][g]={d,m} (for the
// register-resident transposed main path). No Ainv fill, no Cholesky.
// Fallback: Cholesky + triangular inverse, writes Ainv.
// gflag[g] written unconditionally (0=diag, 1=general) -> no memset needed.
// ---------------------------------------------------------------------------
__global__ __launch_bounds__(64)
void gm_setup(const float* __restrict__ centers,
              const float* __restrict__ cov,
              float* __restrict__ Ainv,    // G*F*F  (general path only)
              float* __restrict__ diagv,   // G*F    row-major diag of Linv
              float* __restrict__ mvec,    // G*F    row-major m
              float* __restrict__ cmT,     // F*G*2  transposed {d,m} pairs
              float* __restrict__ kconst,  // G
              int*   __restrict__ gflag)   // G
{
    __shared__ float a[F_DIM][F_DIM + 1];
    __shared__ float y[F_DIM][F_DIM + 1];
    __shared__ float ld[F_DIM];
    __shared__ float dsh[F_DIM];
    const int g = blockIdx.x;
    const int t = threadIdx.x;   // 0..63
    const float* covg = cov + (size_t)g * F_DIM * F_DIM;

    // Coalesced sweep: check off-diagonals, capture diagonal values.
    int bad = 0;
    const float4* cov4 = (const float4*)covg;
#pragma unroll
    for (int i = 0; i < 16; ++i) {
        const float4 v = cov4[i * 64 + t];
        const int base = (i * 64 + t) * 4;
        const float vv[4] = {v.x, v.y, v.z, v.w};
#pragma unroll
        for (int c = 0; c < 4; ++c) {
            const int flat = base + c;
            const int r = flat >> 6, col = flat & 63;
            if (r == col) dsh[r] = vv[c];
            else if (vv[c] != 0.0f) bad = 1;
        }
    }
    const unsigned long long anybad = __ballot(bad);
    __syncthreads();

    if (t == 0) gflag[g] = (anybad != 0ull) ? 1 : 0;

    if (anybad == 0ull) {
        // -------- diagonal fast path: coefficients only --------
        const float d  = dsh[t];
        const float rs = 1.0f / sqrtf(d);
        const float m  = centers[g * F_DIM + t] * rs;
        diagv[g * F_DIM + t] = rs;
        mvec[g * F_DIM + t]  = m;
        float2 dm; dm.x = rs; dm.y = m;
        *(float2*)(cmT + (size_t)(t * G_DIM + g) * 2) = dm;  // [dim][g]

        float lg = logf(d);
#pragma unroll
        for (int off = 1; off < 64; off <<= 1) lg += __shfl_xor(lg, off);
        if (t == 0) kconst[g] = lg + (float)F_DIM * LOG2PI;
        return;
    }

    // -------- general fallback: Cholesky + inverse --------
    for (int j = 0; j < F_DIM; ++j) a[t][j] = covg[t * F_DIM + j];
    __syncthreads();

    for (int j = 0; j < F_DIM; ++j) {
        if (t == j) a[j][j] = sqrtf(a[j][j]);
        __syncthreads();
        if (t > j) a[t][j] /= a[j][j];
        __syncthreads();
        if (t > j) {
            const float ltj = a[t][j];
            for (int k = j + 1; k <= t; ++k) a[t][k] -= ltj * a[k][j];
        }
        __syncthreads();
    }

    ld[t] = logf(a[t][t]);

    {   // thread t owns column t of Linv
        const int c = t;
        for (int i = 0; i < c; ++i) y[i][c] = 0.0f;
        y[c][c] = 1.0f / a[c][c];
        for (int i = c + 1; i < F_DIM; ++i) {
            float s = 0.0f;
            for (int k = c; k < i; ++k) s += a[i][k] * y[k][c];
            y[i][c] = -s / a[i][i];
        }
    }
    __syncthreads();

    for (int j = 0; j < F_DIM; ++j)
        Ainv[(size_t)g * F_DIM * F_DIM + t * F_DIM + j] = y[t][j];
    diagv[g * F_DIM + t] = y[t][t];

    const float* cg = centers + g * F_DIM;
    float s = 0.0f;
    for (int j = 0; j <= t; ++j) s += y[t][j] * cg[j];
    mvec[g * F_DIM + t] = s;

    if (t == 0) {
        float sum = 0.0f;
        for (int j = 0; j < F_DIM; ++j) sum += ld[j];
        kconst[g] = 2.0f * sum + (float)F_DIM * LOG2PI;
    }
}

// ---------------------------------------------------------------------------
// Main, 1D grid of npts/32 blocks x 256 threads.
// All-diag fast path (transposed): lane = gaussian, coefficients in VGPRs,
//   x row read wave-uniformly (broadcast / s_load), zero LDS in inner loop.
//   Wave w of block b handles points b*32 + w*8 .. +8.
// Mixed/general fallback: decode pblk = bid>>3, g0 = (bid&7)*GPB -> identical
//   work split to the old (npts/256, 8) 2D grid.
// ---------------------------------------------------------------------------
__global__ __launch_bounds__(PTS)
void gm_main(const float* __restrict__ x,
             const float* __restrict__ Ainv,
             const float* __restrict__ diagv,
             const float* __restrict__ mvec,
             const float* __restrict__ cmT,
             const float* __restrict__ kconst,
             const int* __restrict__ gflag,
             float* __restrict__ out)
{
    __shared__ float As[F_DIM * F_DIM];   // general path only
    __shared__ float Ds[GPB * F_DIM];
    __shared__ float Ms[GPB * F_DIM];
    __shared__ float Kc[GPB];
    const int t = threadIdx.x;
    const int lane = t & 63;

    // Block-uniform: every wave's lanes 0..63 read gflag[0..63].
    const int anyoff = __any(gflag[lane] != 0);

    if (!anyoff) {
        // ---------------- transposed all-diag fast path ----------------
        // Coefficients for gaussian `lane` -> registers (loaded coalesced).
        float2 dm[F_DIM];
        const float2* cm = (const float2*)cmT + lane;   // stride G_DIM float2s
#pragma unroll
        for (int j = 0; j < F_DIM; ++j) dm[j] = cm[(size_t)j * G_DIM];
        const float kg = kconst[lane];

        const int w = __builtin_amdgcn_readfirstlane(t >> 6);
        const int pbase = blockIdx.x * (4 * PPW) + w * PPW;

        for (int i = 0; i < PPW; ++i) {
            const int p = pbase + i;
            const float4* xrow = (const float4*)(x + (size_t)p * F_DIM);
            float a0 = 0.0f, a1 = 0.0f, a2 = 0.0f, a3 = 0.0f;
#pragma unroll
            for (int j4 = 0; j4 < F_DIM / 4; ++j4) {
                const float4 xv = xrow[j4];   // wave-uniform -> broadcast
                const float z0 = fmaf(xv.x, dm[4 * j4 + 0].x, -dm[4 * j4 + 0].y);
                const float z1 = fmaf(xv.y, dm[4 * j4 + 1].x, -dm[4 * j4 + 1].y);
                const float z2 = fmaf(xv.z, dm[4 * j4 + 2].x, -dm[4 * j4 + 2].y);
                const float z3 = fmaf(xv.w, dm[4 * j4 + 3].x, -dm[4 * j4 + 3].y);
                a0 = fmaf(z0, z0, a0);
                a1 = fmaf(z1, z1, a1);
                a2 = fmaf(z2, z2, a2);
                a3 = fmaf(z3, z3, a3);
            }
            const float maha = (a0 + a1) + (a2 + a3);
            out[(size_t)p * G_DIM + lane] = __expf(-0.5f * (maha + kg));
        }
        return;
    }

    // ---------------- mixed / general path ----------------
    const int pblk = blockIdx.x >> 3;
    const int g0   = (blockIdx.x & 7) * GPB;
    const size_t p = (size_t)pblk * PTS + t;

    float xr[F_DIM];
    const float4* xp = (const float4*)(x + p * F_DIM);
#pragma unroll
    for (int j = 0; j < F_DIM / 4; ++j) {
        const float4 v = xp[j];
        xr[4 * j + 0] = v.x; xr[4 * j + 1] = v.y;
        xr[4 * j + 2] = v.z; xr[4 * j + 3] = v.w;
    }

    ((float2*)Ds)[t] = ((const float2*)(diagv + g0 * F_DIM))[t];
    ((float2*)Ms)[t] = ((const float2*)(mvec  + g0 * F_DIM))[t];
    if (t < GPB) Kc[t] = kconst[g0 + t];
    __syncthreads();

    float o[GPB];
    for (int gi = 0; gi < GPB; ++gi) {
        const int g = g0 + gi;
        float maha = 0.0f;
        if (gflag[g] == 0) {           // block-uniform branch
            const float4* dv = (const float4*)(Ds + gi * F_DIM);
            const float4* mv = (const float4*)(Ms + gi * F_DIM);
            float m0 = 0.0f, m1 = 0.0f, m2 = 0.0f, m3 = 0.0f;
#pragma unroll
            for (int j = 0; j < F_DIM / 4; ++j) {
                const float4 d = dv[j];
                const float4 m = mv[j];
                const float z0 = fmaf(xr[4 * j + 0], d.x, -m.x);
                const float z1 = fmaf(xr[4 * j + 1], d.y, -m.y);
                const float z2 = fmaf(xr[4 * j + 2], d.z, -m.z);
                const float z3 = fmaf(xr[4 * j + 3], d.w, -m.w);
                m0 = fmaf(z0, z0, m0);
                m1 = fmaf(z1, z1, m1);
                m2 = fmaf(z2, z2, m2);
                m3 = fmaf(z3, z3, m3);
            }
            maha = (m0 + m1) + (m2 + m3);
        } else {
            __syncthreads();   // As reuse (uniform: gflag same blockwide)
            const float4* Ag = (const float4*)(Ainv + (size_t)g * F_DIM * F_DIM);
            float4* As4 = (float4*)As;
#pragma unroll
            for (int r = 0; r < 4; ++r) As4[r * PTS + t] = Ag[r * PTS + t];
            __syncthreads();
#pragma unroll 8
            for (int i = 0; i < F_DIM; ++i) {
                const float4* row = (const float4*)(As + i * F_DIM);
                float a0 = 0.0f, a1 = 0.0f, a2 = 0.0f, a3 = 0.0f;
#pragma unroll
                for (int j = 0; j < F_DIM / 4; ++j) {
                    const float4 v = row[j];
                    a0 = fmaf(v.x, xr[4 * j + 0], a0);
                    a1 = fmaf(v.y, xr[4 * j + 1], a1);
                    a2 = fmaf(v.z, xr[4 * j + 2], a2);
                    a3 = fmaf(v.w, xr[4 * j + 3], a3);
                }
                const float z = ((a0 + a2) + (a1 + a3)) - Ms[gi * F_DIM + i];
                maha = fmaf(z, z, maha);
            }
        }
        o[gi] = __expf(-0.5f * (maha + Kc[gi]));
    }
#pragma unroll
    for (int gi = 0; gi < GPB; ++gi) out[p * G_DIM + g0 + gi] = o[gi];
}

// ---------------------------------------------------------------------------
extern "C" void kernel_launch(void* const* d_in, const int* in_sizes, int n_in,
                              void* d_out, int out_size, void* d_ws, size_t ws_size,
                              hipStream_t stream) {
    const float* x       = (const float*)d_in[0];
    const float* centers = (const float*)d_in[1];
    const float* cov     = (const float*)d_in[2];
    float* out = (float*)d_out;

    char* ws = (char*)d_ws;
    const size_t ainv_bytes = (size_t)G_DIM * F_DIM * F_DIM * sizeof(float); // 1 MiB
    const size_t gf_bytes   = (size_t)G_DIM * F_DIM * sizeof(float);         // 16 KiB
    float* Ainv   = (float*)(ws);
    float* mvec   = (float*)(ws + ainv_bytes);
    float* kconst = (float*)(ws + ainv_bytes + gf_bytes);
    float* diagv  = (float*)(ws + ainv_bytes + gf_bytes + 1024);
    int*   gflag  = (int*)  (ws + ainv_bytes + gf_bytes + 1024 + gf_bytes);
    float* cmT    = (float*)(ws + ainv_bytes + gf_bytes + 1024 + gf_bytes + 1024);

    const int npts = in_sizes[0] / F_DIM;   // 16384

    gm_setup<<<G_DIM, F_DIM, 0, stream>>>(centers, cov, Ainv, diagv, mvec,
                                          cmT, kconst, gflag);

    gm_main<<<npts / (4 * PPW), PTS, 0, stream>>>(x, Ainv, diagv, mvec, cmT,
                                                  kconst, gflag, out);
}